// Round 5
// baseline (404.073 us; speedup 1.0000x reference)
//
#include <hip/hip_runtime.h>

// PLoss fused kernel, round 7.
// Round-6 post-mortem: still spilling. VGPR_Count=84 (=512/6!), WRITE=159.9 MB,
// FETCH=448 MB. Diagnosis: __launch_bounds__(256,3) only CAPS registers at the
// 3-wave budget; the allocator's own heuristic targeted 6 waves/EU and chose
// 84 VGPR + scratch spills, even though LDS (33.8 KB) limits us to 4 blocks/CU
// (4 waves/EU) anyway. The 6-wave target was unreachable; the spills were pure
// loss.
// Changes this round:
//  - __attribute__((amdgpu_waves_per_eu(4,4))): pin occupancy target = LDS
//    limit = 4 waves/EU -> register budget 512/4 = 128, no incentive to spill.
//  - Remove the register prefetch double-buffer (-32 VGPR, peak live ~95-100).
//    T14-null rationale: memory-bound streaming at 16 waves/CU hides HBM
//    latency via TLP (slack ~8x: 1.6k cy serial chain vs 13k cy BW period).
// Retained: x loaded directly in MFMA-A fragment layout (no x_lds, no pack,
// no per-tile barriers); softmax/h2 quad-axis shfl reduce; lse in-register;
// argmin d^2/2 >= 0 as plain uint min (7-bit idx in mantissa LSBs); MFMA in
// 2 passes of 4 n-tiles; f32 scalar epilogue gather; partial[blockIdx].

#define C_DIM 128
#define TILE_ROWS 64
#define NTHREADS 256
#define GRID_MAX 1536
#define NFRAG 32              // 8 n-tiles * 4 k-tiles

typedef __bf16 bf16x8 __attribute__((ext_vector_type(8)));
typedef unsigned short ushort8 __attribute__((ext_vector_type(8)));
typedef float f32x4 __attribute__((ext_vector_type(4)));

union FragU { ushort8 u; bf16x8 b; };

__device__ __forceinline__ unsigned short f2bf(float f) {   // prologue staging only
    unsigned int u = __float_as_uint(f);
    u += 0x7fffu + ((u >> 16) & 1u);   // round-to-nearest-even
    return (unsigned short)(u >> 16);
}
__device__ __forceinline__ float fmax4(float4 v) {
    return fmaxf(fmaxf(v.x, v.y), fmaxf(v.z, v.w));
}
__device__ __forceinline__ float esum4(float4 v, float m) {
    return __expf(v.x - m) + __expf(v.y - m) + __expf(v.z - m) + __expf(v.w - m);
}
__device__ __forceinline__ float dot4(float4 v) {
    return v.x*v.x + v.y*v.y + v.z*v.z + v.w*v.w;
}
__device__ __forceinline__ bf16x8 cvt8(float4 lo, float4 hi) {
    bf16x8 r;
    r[0]=(__bf16)lo.x; r[1]=(__bf16)lo.y; r[2]=(__bf16)lo.z; r[3]=(__bf16)lo.w;
    r[4]=(__bf16)hi.x; r[5]=(__bf16)hi.y; r[6]=(__bf16)hi.z; r[7]=(__bf16)hi.w;
    return r;
}

extern "C" __global__ void __attribute__((amdgpu_waves_per_eu(4, 4)))
__launch_bounds__(NTHREADS)
ploss_main(const float* __restrict__ x, const int* __restrict__ labels,
           const float* __restrict__ protos, const int* __restrict__ kptr,
           float* __restrict__ partial, int n_tiles, int n_rows)
{
    // 32768 + 512 + 16 = 33.3 KB -> 4 blocks/CU (LDS-bound), matching wpEU=4
    __shared__ __attribute__((aligned(16))) unsigned short blds[NFRAG * 64 * 8];
    __shared__ float norm_lds[C_DIM];
    __shared__ float wsum[4];

    const int tid  = threadIdx.x;
    const int lane = tid & 63;
    const int wave = tid >> 6;
    const int l15  = lane & 15;
    const int quad = lane >> 4;
    const int wrow = wave * 16;
    const int kk   = kptr[0];

    // ---- prologue: proto squared norms (2 threads per proto) ----
    {
        const int j = tid >> 1;
        const float* pr = protos + j * C_DIM + (tid & 1) * 64;
        float s = 0.f;
#pragma unroll
        for (int c = 0; c < 64; c += 4) {
            float4 v = *(const float4*)(pr + c);
            s += dot4(v);
        }
        s += __shfl_xor(s, 1);
        if ((tid & 1) == 0) norm_lds[j] = s;
    }
    // ---- prologue: protos -> frag-linear bf16 MFMA-B fragments in LDS ----
    // frag id = nt*4+kt; lane l holds col nt*16+(l&15), k = kt*32+(l>>4)*8..+8
#pragma unroll
    for (int f = 0; f < 8; ++f) {
        const int g = f * NTHREADS + tid;       // 0..2047 = frag*64 + lane
        const int l = g & 63;
        const int frag = g >> 6;
        const int nt = frag >> 2, kt = frag & 3;
        const float* pp = protos + (nt * 16 + (l & 15)) * C_DIM + kt * 32 + (l >> 4) * 8;
        float4 v0 = *(const float4*)(pp);
        float4 v1 = *(const float4*)(pp + 4);
        FragU fr;
        fr.u[0]=f2bf(v0.x); fr.u[1]=f2bf(v0.y); fr.u[2]=f2bf(v0.z); fr.u[3]=f2bf(v0.w);
        fr.u[4]=f2bf(v1.x); fr.u[5]=f2bf(v1.y); fr.u[6]=f2bf(v1.z); fr.u[7]=f2bf(v1.w);
        *(ushort8*)&blds[g * 8] = fr.u;
    }
    __syncthreads();   // blds + norm_lds ready; no further barriers until reduce

    float p2h[8];
#pragma unroll
    for (int nt = 0; nt < 8; ++nt) p2h[nt] = 0.5f * norm_lds[nt * 16 + l15];

    float nll_acc = 0.f;

    for (int t = blockIdx.x; t < n_tiles; t += gridDim.x) {
        // ---- load tile in A-fragment layout ----
        // lane (quad,l15): row = t*64 + wrow + l15, cols kt*32 + quad*8 + 0..7
        float4 a[8];
        int lab = 0;
        {
            long long rb = (long long)t * TILE_ROWS + wrow + l15;
            if (rb >= n_rows) rb = n_rows - 1;
            const float* xr = x + rb * C_DIM;
#pragma unroll
            for (int i = 0; i < 8; ++i)
                a[i] = *(const float4*)(xr + (i >> 1) * 32 + quad * 8 + (i & 1) * 4);
            if (l15 < 4) {
                long long lb = (long long)t * TILE_ROWS + wrow + quad * 4 + l15;
                if (lb >= n_rows) lb = n_rows - 1;
                lab = labels[lb];
            }
        }

        // ---- row stats (reduce over quad axis: masks 16, 32) ----
        float m = fmax4(a[0]);
#pragma unroll
        for (int i = 1; i < 8; ++i) m = fmaxf(m, fmax4(a[i]));
        m = fmaxf(m, __shfl_xor(m, 16));
        m = fmaxf(m, __shfl_xor(m, 32));
        float s = 0.f, h2 = 0.f;
#pragma unroll
        for (int i = 0; i < 8; ++i) { s += esum4(a[i], m); h2 += dot4(a[i]); }
        s  += __shfl_xor(s, 16);  h2 += __shfl_xor(h2, 16);
        s  += __shfl_xor(s, 32);  h2 += __shfl_xor(h2, 32);
        const float lse = m + __logf(s);
        h2 *= 0.5f;                          // 0.5*||x_row||^2, row = l15

        // ---- A fragments: in-register bf16 convert (a[] dies here) ----
        FragU A[4];
#pragma unroll
        for (int kt = 0; kt < 4; ++kt) A[kt].b = cvt8(a[2 * kt], a[2 * kt + 1]);

        // per-acc-row constants: acc C-row = quad*4+rg, its h2 lives in lane row
        float hp[4];
#pragma unroll
        for (int rg = 0; rg < 4; ++rg) hp[rg] = __shfl(h2, quad * 4 + rg);
        const float lse_r = __shfl(lse, quad * 4 + l15);  // epilogue lse (l15<4)

        // ---- MFMA + packed argmin, 2 passes of 4 n-tiles (acc = 16 VGPR) ----
        unsigned um0 = 0xFFFFFFFFu, um1 = 0xFFFFFFFFu,
                 um2 = 0xFFFFFFFFu, um3 = 0xFFFFFFFFu;
#pragma unroll
        for (int pass = 0; pass < 2; ++pass) {
            f32x4 acc[4];
            f32x4 zero = {0.f, 0.f, 0.f, 0.f};
#pragma unroll
            for (int nti = 0; nti < 4; ++nti) acc[nti] = zero;
#pragma unroll
            for (int kt = 0; kt < 4; ++kt) {
#pragma unroll
                for (int nti = 0; nti < 4; ++nti) {
                    const int nt = pass * 4 + nti;
                    FragU B;
                    B.u = *(const ushort8*)&blds[((nt * 4 + kt) * 64 + lane) * 8];
                    acc[nti] = __builtin_amdgcn_mfma_f32_16x16x32_bf16(
                                   A[kt].b, B.b, acc[nti], 0, 0, 0);
                }
            }
            // score = d^2/2 = h2(row) + p2h(col) - x.p  (>= 0 -> uint-ordered)
#pragma unroll
            for (int nti = 0; nti < 4; ++nti) {
                const int nt = pass * 4 + nti;
                const unsigned idx = (unsigned)(nt * 16 + l15);
                {
                    unsigned c = (__float_as_uint((hp[0] + p2h[nt]) - acc[nti][0]) & 0xFFFFFF80u) | idx;
                    um0 = c < um0 ? c : um0;
                }
                {
                    unsigned c = (__float_as_uint((hp[1] + p2h[nt]) - acc[nti][1]) & 0xFFFFFF80u) | idx;
                    um1 = c < um1 ? c : um1;
                }
                {
                    unsigned c = (__float_as_uint((hp[2] + p2h[nt]) - acc[nti][2]) & 0xFFFFFF80u) | idx;
                    um2 = c < um2 ? c : um2;
                }
                {
                    unsigned c = (__float_as_uint((hp[3] + p2h[nt]) - acc[nti][3]) & 0xFFFFFF80u) | idx;
                    um3 = c < um3 ? c : um3;
                }
            }
        }
        // cross-l15 reduce (masks 1..8 stay within the 16-lane quad group)
#pragma unroll
        for (int mask = 1; mask <= 8; mask <<= 1) {
            unsigned o0 = __shfl_xor(um0, mask); um0 = o0 < um0 ? o0 : um0;
            unsigned o1 = __shfl_xor(um1, mask); um1 = o1 < um1 ? o1 : um1;
            unsigned o2 = __shfl_xor(um2, mask); um2 = o2 < um2 ? o2 : um2;
            unsigned o3 = __shfl_xor(um3, mask); um3 = o3 < um3 ? o3 : um3;
        }
        const int rs = l15 & 3;
        const unsigned ur = rs == 0 ? um0 : rs == 1 ? um1 : rs == 2 ? um2 : um3;

        // ---- epilogue: 16 lanes/wave, one row each; f32 scalar gather ----
        if (l15 < 4) {
            const long long grow = (long long)t * TILE_ROWS + wrow + quad * 4 + l15;
            if (grow < n_rows) {
                const int bj  = (int)(ur & 127u);
                const int eff = (lab <= kk - 1) ? lab : bj;
                const float xv = x[grow * C_DIM + eff];   // L1/L2 hit (just streamed)
                nll_acc += lse_r - xv;
            }
        }
    }

    // ---- block reduce -> per-block partial (no atomics, no memset) ----
    float v = nll_acc;
#pragma unroll
    for (int mask = 1; mask <= 32; mask <<= 1) v += __shfl_xor(v, mask);
    if (lane == 0) wsum[wave] = v;
    __syncthreads();
    if (tid == 0) partial[blockIdx.x] = wsum[0] + wsum[1] + wsum[2] + wsum[3];
}

extern "C" __global__ void __launch_bounds__(256)
ploss_finalize(const float* __restrict__ partial, float* __restrict__ out,
               float inv_n, int nparts)
{
    __shared__ double sm[4];
    const int tid = threadIdx.x, lane = tid & 63, wave = tid >> 6;
    double v = 0.0;
    for (int i = tid; i < nparts; i += 256) v += (double)partial[i];
#pragma unroll
    for (int mask = 1; mask <= 32; mask <<= 1) v += __shfl_xor(v, mask);
    if (lane == 0) sm[wave] = v;
    __syncthreads();
    if (tid == 0) out[0] = (float)((sm[0] + sm[1] + sm[2] + sm[3]) * (double)inv_n);
}

extern "C" void kernel_launch(void* const* d_in, const int* in_sizes, int n_in,
                              void* d_out, int out_size, void* d_ws, size_t ws_size,
                              hipStream_t stream)
{
    const float* x      = (const float*)d_in[0];
    const int*   labels = (const int*)d_in[1];
    const float* protos = (const float*)d_in[2];
    const int*   kptr   = (const int*)d_in[3];
    const int n_rows  = in_sizes[0] / C_DIM;                 // element counts
    const int n_tiles = (n_rows + TILE_ROWS - 1) / TILE_ROWS; // 400000/64 = 6250

    float* partial = (float*)d_ws;   // overwritten every call; poison-safe

    int grid = GRID_MAX;
    if (grid > n_tiles) grid = n_tiles;
    const int max_parts = (int)(ws_size / sizeof(float));    // workspace guard
    if (grid > max_parts) grid = max_parts;
    if (grid < 1) grid = 1;

    ploss_main<<<grid, NTHREADS, 0, stream>>>(x, labels, protos, kptr, partial,
                                              n_tiles, n_rows);
    ploss_finalize<<<1, 256, 0, stream>>>(partial, (float*)d_out,
                                          1.0f / (float)n_rows, grid);
}

// Round 6
// 297.372 us; speedup vs baseline: 1.3588x; 1.3588x over previous
//
#include <hip/hip_runtime.h>

// PLoss fused kernel, round 8 (= verified round-4 structure + native bf16 cvt).
// Rounds 5-7 post-mortem: the direct-fragment-load redesign spills no matter
// what occupancy hints are given (VGPR_Count 64/84/64, WRITE_SIZE ~150 MB of
// scratch, FETCH 2x mandatory, 202-226 us). The allocator targets 6-8 waves/EU
// on its own heuristic and spills the working set to get there; launch_bounds
// and amdgpu_waves_per_eu hints did not move it. The round-4 kernel - same
// (256,3) bounds, HIGHER nominal live set, but with the x->LDS->fragment
// round-trip - allocated cleanly and measured 298.3 us total (ploss ~53 us).
// Decision: revert to round-4 byte-for-byte, one local delta only:
//  - Hot-loop + prologue bf16 pack via native (__bf16) casts (compiler emits
//    v_cvt_pk_bf16_f32, RTNE - bit-identical values) instead of hand-RTNE
//    f2bf (~160 VALU -> ~16 per thread-tile).
// Retained verified structure:
//  - Wave-private 64-row tiles: wave w owns rows w*16..w*16+15, all 128 cols;
//    ZERO per-tile barriers (wave-private LDS + lgkmcnt fence).
//  - Protos staged once as frag-linear bf16 MFMA-B fragments in LDS (32 KB).
//  - Register double-buffer prefetch of next tile's x + labels.
//  - x packed to single wave-private x_lds buffer; A-frags re-read per kt.
//  - f2ord packed argmin (7-bit idx in mantissa LSBs), 8 candidates + 4 shfl.
//  - Epilogue: 4 lanes/wave, lse from lse_lds, xv from bf16 x_lds.
//  - partial[blockIdx] overwrite + ws-size guard; finalize sums in double.

#define C_DIM 128
#define TILE_ROWS 64
#define NTHREADS 256
#define XSTRIDE 136           // ushorts per x row: 128 + 8 pad
#define GRID_MAX 1536
#define NFRAG 32              // 8 n-tiles * 4 k-tiles

typedef __bf16 bf16x8 __attribute__((ext_vector_type(8)));
typedef unsigned short ushort8 __attribute__((ext_vector_type(8)));
typedef float f32x4 __attribute__((ext_vector_type(4)));

union FragU { ushort8 u; bf16x8 b; };

__device__ __forceinline__ float bf2f(unsigned short h) {
    return __uint_as_float(((unsigned int)h) << 16);
}
// order-preserving float->uint (min-compatible)
__device__ __forceinline__ unsigned f2ord(float s) {
    unsigned u = __float_as_uint(s);
    return (u & 0x80000000u) ? ~u : (u | 0x80000000u);
}
__device__ __forceinline__ float fmax4(float4 v) {
    return fmaxf(fmaxf(v.x, v.y), fmaxf(v.z, v.w));
}
__device__ __forceinline__ float esum4(float4 v, float m) {
    return __expf(v.x - m) + __expf(v.y - m) + __expf(v.z - m) + __expf(v.w - m);
}
__device__ __forceinline__ float dot4(float4 v) {
    return v.x*v.x + v.y*v.y + v.z*v.z + v.w*v.w;
}
__device__ __forceinline__ bf16x8 cvt8(float4 lo, float4 hi) {   // RTNE, packed
    bf16x8 r;
    r[0]=(__bf16)lo.x; r[1]=(__bf16)lo.y; r[2]=(__bf16)lo.z; r[3]=(__bf16)lo.w;
    r[4]=(__bf16)hi.x; r[5]=(__bf16)hi.y; r[6]=(__bf16)hi.z; r[7]=(__bf16)hi.w;
    return r;
}

extern "C" __global__ void __launch_bounds__(NTHREADS, 3)
ploss_main(const float* __restrict__ x, const int* __restrict__ labels,
           const float* __restrict__ protos, const int* __restrict__ kptr,
           float* __restrict__ partial, int n_tiles, int n_rows)
{
    // 32768 + 17408 + 256 + 512 + 16 = 50.9 KB -> 3 blocks/CU
    __shared__ __attribute__((aligned(16))) unsigned short blds[NFRAG * 64 * 8];
    __shared__ __attribute__((aligned(16))) unsigned short x_lds[TILE_ROWS * XSTRIDE];
    __shared__ float lse_lds[TILE_ROWS];
    __shared__ float norm_lds[C_DIM];
    __shared__ float wsum[4];

    const int tid  = threadIdx.x;
    const int lane = tid & 63;
    const int wave = tid >> 6;
    const int l15  = lane & 15;
    const int quad = lane >> 4;
    const int r_l  = lane >> 2;         // row 0..15 within wave's 16 (load/softmax)
    const int c_l  = (lane & 3) * 32;   // 32-col chunk within row
    const int wrow = wave * 16;
    const bool epi = (l15 == 0);
    const int kk   = kptr[0];

    // ---- prologue: proto squared norms (2 threads per proto) ----
    {
        const int j = tid >> 1;
        const float* pr = protos + j * C_DIM + (tid & 1) * 64;
        float s = 0.f;
#pragma unroll
        for (int c = 0; c < 64; c += 4) {
            float4 v = *(const float4*)(pr + c);
            s += dot4(v);
        }
        s += __shfl_xor(s, 1);
        if ((tid & 1) == 0) norm_lds[j] = s;
    }
    // ---- prologue: protos -> frag-linear bf16 MFMA-B fragments in LDS ----
    // frag id = nt*4+kt; lane l holds col nt*16+(l&15), k = kt*32+(l>>4)*8..+8
#pragma unroll
    for (int f = 0; f < 8; ++f) {
        const int g = f * NTHREADS + tid;       // 0..2047 = frag*64 + lane
        const int l = g & 63;
        const int frag = g >> 6;
        const int nt = frag >> 2, kt = frag & 3;
        const float* pp = protos + (nt * 16 + (l & 15)) * C_DIM + kt * 32 + (l >> 4) * 8;
        float4 v0 = *(const float4*)(pp);
        float4 v1 = *(const float4*)(pp + 4);
        FragU fr;
        fr.b = cvt8(v0, v1);
        *(ushort8*)&blds[g * 8] = fr.u;
    }
    __syncthreads();   // blds + norm_lds ready; no further barriers until reduce

    float p2h[8];
#pragma unroll
    for (int nt = 0; nt < 8; ++nt) p2h[nt] = 0.5f * norm_lds[nt * 16 + l15];

    float nll_acc = 0.f;

    // ---- prologue: load first tile into registers ----
    int t = blockIdx.x;
    float4 a[8];
    int4 lab4 = {0, 0, 0, 0};
    {
        long long rb = (long long)t * TILE_ROWS + wrow + r_l;
        if (rb >= n_rows) rb = n_rows - 1;
        const float* xr = x + rb * C_DIM + c_l;
#pragma unroll
        for (int i = 0; i < 8; ++i) a[i] = *(const float4*)(xr + i * 4);
        if (epi) {
            long long lb = (long long)t * TILE_ROWS + wrow + quad * 4;
            if (lb > (long long)n_rows - 4) lb = n_rows - 4;
            lab4 = *(const int4*)(labels + lb);
        }
    }

    for (; t < n_tiles; t += gridDim.x) {
        // ---- prefetch next tile (x + labels) into shadow registers ----
        const int tn = t + gridDim.x;
        const int tl = (tn < n_tiles) ? tn : t;    // clamp: tail load discarded
        float4 b[8];
        int4 labn4 = lab4;
        {
            long long rb = (long long)tl * TILE_ROWS + wrow + r_l;
            if (rb >= n_rows) rb = n_rows - 1;
            const float* xr = x + rb * C_DIM + c_l;
#pragma unroll
            for (int i = 0; i < 8; ++i) b[i] = *(const float4*)(xr + i * 4);
            if (epi) {
                long long lb = (long long)tl * TILE_ROWS + wrow + quad * 4;
                if (lb > (long long)n_rows - 4) lb = n_rows - 4;
                labn4 = *(const int4*)(labels + lb);
            }
        }

        // ---- softmax stats (4 lanes per row, depth-2 reduce) ----
        float m = fmax4(a[0]);
#pragma unroll
        for (int i = 1; i < 8; ++i) m = fmaxf(m, fmax4(a[i]));
        float s = 0.f;
#pragma unroll
        for (int i = 0; i < 8; ++i) s += esum4(a[i], m);
#pragma unroll
        for (int mask = 1; mask <= 2; mask <<= 1) {
            float mo = __shfl_xor(m, mask);
            float so = __shfl_xor(s, mask);
            float nm = fmaxf(m, mo);
            s = s * __expf(m - nm) + so * __expf(mo - nm);
            m = nm;
        }
        if ((lane & 3) == 0) lse_lds[wrow + r_l] = m + __logf(s);

        // ---- bf16 convert -> wave-private LDS rows (native packed cvt) ----
        ushort8* dst = (ushort8*)&x_lds[(wrow + r_l) * XSTRIDE + c_l];
#pragma unroll
        for (int i = 0; i < 4; ++i) {
            FragU wv;
            wv.b = cvt8(a[2 * i], a[2 * i + 1]);
            dst[i] = wv.u;
        }
        // same-wave DS ordering: drain writes before fragment reads (no barrier)
        asm volatile("s_waitcnt lgkmcnt(0)" ::: "memory");
        __builtin_amdgcn_sched_barrier(0);

        // ---- MFMA: this wave's 16 rows x all 128 protos ----
        FragU A[4];
#pragma unroll
        for (int kt = 0; kt < 4; ++kt)
            A[kt].u = *(const ushort8*)&x_lds[(wrow + l15) * XSTRIDE + kt * 32 + quad * 8];
        f32x4 acc[8];
        f32x4 zero = {0.f, 0.f, 0.f, 0.f};
#pragma unroll
        for (int nt = 0; nt < 8; ++nt) acc[nt] = zero;
#pragma unroll
        for (int kt = 0; kt < 4; ++kt) {
#pragma unroll
            for (int nt = 0; nt < 8; ++nt) {
                FragU B;
                B.u = *(const ushort8*)&blds[((nt * 4 + kt) * 64 + lane) * 8];
                acc[nt] = __builtin_amdgcn_mfma_f32_16x16x32_bf16(A[kt].b, B.b, acc[nt], 0, 0, 0);
            }
        }

        // ---- in-wave packed argmin over all 128 cols ----
        // C layout: col = nt*16 + l15, row = quad*4 + rg
        unsigned res[4];
#pragma unroll
        for (int rg = 0; rg < 4; ++rg) {
            unsigned u = 0xFFFFFFFFu;
#pragma unroll
            for (int nt = 0; nt < 8; ++nt) {
                unsigned c = (f2ord(p2h[nt] - acc[nt][rg]) & 0xFFFFFF80u)
                           | (unsigned)(nt * 16 + l15);
                u = (c < u) ? c : u;
            }
#pragma unroll
            for (int mask = 1; mask <= 8; mask <<= 1) {
                unsigned uo = __shfl_xor(u, mask);
                u = (uo < u) ? uo : u;
            }
            res[rg] = u;
        }

        // ---- per-wave epilogue (4 lanes, rows quad*4..quad*4+3) ----
        if (epi) {
#pragma unroll
            for (int rg = 0; rg < 4; ++rg) {
                const int row16 = quad * 4 + rg;
                const long long grow = (long long)t * TILE_ROWS + wrow + row16;
                if (grow < n_rows) {
                    int lab;
                    if      (rg == 0) lab = lab4.x;
                    else if (rg == 1) lab = lab4.y;
                    else if (rg == 2) lab = lab4.z;
                    else              lab = lab4.w;
                    const int bj  = (int)(res[rg] & 127u);
                    const int eff = (lab <= kk - 1) ? lab : bj;
                    const float xv = bf2f(x_lds[(wrow + row16) * XSTRIDE + eff]);
                    nll_acc += lse_lds[wrow + row16] - xv;
                }
            }
        }

        // rotate prefetch buffers
#pragma unroll
        for (int i = 0; i < 8; ++i) a[i] = b[i];
        lab4 = labn4;
    }

    // ---- block reduce -> per-block partial (no atomics, no memset) ----
    float v = nll_acc;
#pragma unroll
    for (int mask = 1; mask <= 32; mask <<= 1) v += __shfl_xor(v, mask);
    if (lane == 0) wsum[wave] = v;
    __syncthreads();
    if (tid == 0) partial[blockIdx.x] = wsum[0] + wsum[1] + wsum[2] + wsum[3];
}

extern "C" __global__ void __launch_bounds__(256)
ploss_finalize(const float* __restrict__ partial, float* __restrict__ out,
               float inv_n, int nparts)
{
    __shared__ double sm[4];
    const int tid = threadIdx.x, lane = tid & 63, wave = tid >> 6;
    double v = 0.0;
    for (int i = tid; i < nparts; i += 256) v += (double)partial[i];
#pragma unroll
    for (int mask = 1; mask <= 32; mask <<= 1) v += __shfl_xor(v, mask);
    if (lane == 0) sm[wave] = v;
    __syncthreads();
    if (tid == 0) out[0] = (float)((sm[0] + sm[1] + sm[2] + sm[3]) * (double)inv_n);
}

extern "C" void kernel_launch(void* const* d_in, const int* in_sizes, int n_in,
                              void* d_out, int out_size, void* d_ws, size_t ws_size,
                              hipStream_t stream)
{
    const float* x      = (const float*)d_in[0];
    const int*   labels = (const int*)d_in[1];
    const float* protos = (const float*)d_in[2];
    const int*   kptr   = (const int*)d_in[3];
    const int n_rows  = in_sizes[0] / C_DIM;                 // element counts
    const int n_tiles = (n_rows + TILE_ROWS - 1) / TILE_ROWS; // 400000/64 = 6250

    float* partial = (float*)d_ws;   // overwritten every call; poison-safe

    int grid = GRID_MAX;
    if (grid > n_tiles) grid = n_tiles;
    const int max_parts = (int)(ws_size / sizeof(float));    // workspace guard
    if (grid > max_parts) grid = max_parts;
    if (grid < 1) grid = 1;

    ploss_main<<<grid, NTHREADS, 0, stream>>>(x, labels, protos, kptr, partial,
                                              n_tiles, n_rows);
    ploss_finalize<<<1, 256, 0, stream>>>(partial, (float*)d_out,
                                          1.0f / (float)n_rows, grid);
}

// Round 7
// 297.069 us; speedup vs baseline: 1.3602x; 1.0010x over previous
//
#include <hip/hip_runtime.h>

// PLoss fused kernel, round 9 (= round-8 + bias-positive raw-bit argmin).
// Round-8 post-mortem: 297.4 us total; fills ~237 us fixed; ploss_main ~55 us
// vs 33 us HBM floor. Structural levers exhausted: 4 blocks/CU impossible at
// 256 thr (blds 32K + x_lds 16K > 40K), 512-thr/2-block needs a 128-VGPR cap
// = the proven rounds-5-7 spill regime (allocator spills at VGPR=64 even with
// ~95 live). This round trims the largest VALU block instead:
//  - argmin score biased positive: p2b[nt] = 1024 + 0.5||p||^2, so
//    s' = p2b - x.p in (512,2048) -> strictly positive -> raw IEEE bits are
//    uint-min-ordered; f2ord (4 ops) deleted. Inner candidate is now
//    {v_sub_f32, v_and_or_b32, v_min_u32} = 3 VALU; 224 -> 96 VALU/thread/tile.
//    Precision: fixed 2^10 exponent + 7-bit idx truncation -> granularity
//    2^-6 ~ 0.016 in d^2/2 units < existing bf16-dot noise (~0.03-0.05) that
//    already gives absmax 0.0. Tie-break lowest index preserved (jnp.argmin).
// Retained verified structure (round 4/8):
//  - Wave-private 64-row tiles, ZERO per-tile barriers (wave-private LDS +
//    lgkmcnt fence + sched_barrier; fence REQUIRED: x_lds rows are written by
//    different lanes of the same wave - compiler won't order without it).
//  - Protos staged once as frag-linear bf16 MFMA-B fragments in LDS (32 KB).
//  - Register double-buffer prefetch of next tile's x + labels.
//  - Native packed bf16 cvt (v_cvt_pk_bf16_f32) for all f32->bf16.
//  - Epilogue: 4 lanes/wave, lse from lse_lds, xv from bf16 x_lds.
//  - partial[blockIdx] overwrite + ws-size guard; finalize sums in double.

#define C_DIM 128
#define TILE_ROWS 64
#define NTHREADS 256
#define XSTRIDE 136           // ushorts per x row: 128 + 8 pad
#define GRID_MAX 1536
#define NFRAG 32              // 8 n-tiles * 4 k-tiles

typedef __bf16 bf16x8 __attribute__((ext_vector_type(8)));
typedef unsigned short ushort8 __attribute__((ext_vector_type(8)));
typedef float f32x4 __attribute__((ext_vector_type(4)));

union FragU { ushort8 u; bf16x8 b; };

__device__ __forceinline__ float bf2f(unsigned short h) {
    return __uint_as_float(((unsigned int)h) << 16);
}
__device__ __forceinline__ float fmax4(float4 v) {
    return fmaxf(fmaxf(v.x, v.y), fmaxf(v.z, v.w));
}
__device__ __forceinline__ float esum4(float4 v, float m) {
    return __expf(v.x - m) + __expf(v.y - m) + __expf(v.z - m) + __expf(v.w - m);
}
__device__ __forceinline__ float dot4(float4 v) {
    return v.x*v.x + v.y*v.y + v.z*v.z + v.w*v.w;
}
__device__ __forceinline__ bf16x8 cvt8(float4 lo, float4 hi) {   // RTNE, packed
    bf16x8 r;
    r[0]=(__bf16)lo.x; r[1]=(__bf16)lo.y; r[2]=(__bf16)lo.z; r[3]=(__bf16)lo.w;
    r[4]=(__bf16)hi.x; r[5]=(__bf16)hi.y; r[6]=(__bf16)hi.z; r[7]=(__bf16)hi.w;
    return r;
}

extern "C" __global__ void __launch_bounds__(NTHREADS, 3)
ploss_main(const float* __restrict__ x, const int* __restrict__ labels,
           const float* __restrict__ protos, const int* __restrict__ kptr,
           float* __restrict__ partial, int n_tiles, int n_rows)
{
    // 32768 + 17408 + 256 + 512 + 16 = 50.9 KB -> 3 blocks/CU
    __shared__ __attribute__((aligned(16))) unsigned short blds[NFRAG * 64 * 8];
    __shared__ __attribute__((aligned(16))) unsigned short x_lds[TILE_ROWS * XSTRIDE];
    __shared__ float lse_lds[TILE_ROWS];
    __shared__ float norm_lds[C_DIM];
    __shared__ float wsum[4];

    const int tid  = threadIdx.x;
    const int lane = tid & 63;
    const int wave = tid >> 6;
    const int l15  = lane & 15;
    const int quad = lane >> 4;
    const int r_l  = lane >> 2;         // row 0..15 within wave's 16 (load/softmax)
    const int c_l  = (lane & 3) * 32;   // 32-col chunk within row
    const int wrow = wave * 16;
    const bool epi = (l15 == 0);
    const int kk   = kptr[0];

    // ---- prologue: proto squared norms (2 threads per proto) ----
    {
        const int j = tid >> 1;
        const float* pr = protos + j * C_DIM + (tid & 1) * 64;
        float s = 0.f;
#pragma unroll
        for (int c = 0; c < 64; c += 4) {
            float4 v = *(const float4*)(pr + c);
            s += dot4(v);
        }
        s += __shfl_xor(s, 1);
        if ((tid & 1) == 0) norm_lds[j] = s;
    }
    // ---- prologue: protos -> frag-linear bf16 MFMA-B fragments in LDS ----
    // frag id = nt*4+kt; lane l holds col nt*16+(l&15), k = kt*32+(l>>4)*8..+8
#pragma unroll
    for (int f = 0; f < 8; ++f) {
        const int g = f * NTHREADS + tid;       // 0..2047 = frag*64 + lane
        const int l = g & 63;
        const int frag = g >> 6;
        const int nt = frag >> 2, kt = frag & 3;
        const float* pp = protos + (nt * 16 + (l & 15)) * C_DIM + kt * 32 + (l >> 4) * 8;
        float4 v0 = *(const float4*)(pp);
        float4 v1 = *(const float4*)(pp + 4);
        FragU fr;
        fr.b = cvt8(v0, v1);
        *(ushort8*)&blds[g * 8] = fr.u;
    }
    __syncthreads();   // blds + norm_lds ready; no further barriers until reduce

    // biased half-norms: s' = p2b - x.p  in (512, 2048) -> positive, fixed exp
    float p2b[8];
#pragma unroll
    for (int nt = 0; nt < 8; ++nt) p2b[nt] = 1024.0f + 0.5f * norm_lds[nt * 16 + l15];

    float nll_acc = 0.f;

    // ---- prologue: load first tile into registers ----
    int t = blockIdx.x;
    float4 a[8];
    int4 lab4 = {0, 0, 0, 0};
    {
        long long rb = (long long)t * TILE_ROWS + wrow + r_l;
        if (rb >= n_rows) rb = n_rows - 1;
        const float* xr = x + rb * C_DIM + c_l;
#pragma unroll
        for (int i = 0; i < 8; ++i) a[i] = *(const float4*)(xr + i * 4);
        if (epi) {
            long long lb = (long long)t * TILE_ROWS + wrow + quad * 4;
            if (lb > (long long)n_rows - 4) lb = n_rows - 4;
            lab4 = *(const int4*)(labels + lb);
        }
    }

    for (; t < n_tiles; t += gridDim.x) {
        // ---- prefetch next tile (x + labels) into shadow registers ----
        const int tn = t + gridDim.x;
        const int tl = (tn < n_tiles) ? tn : t;    // clamp: tail load discarded
        float4 b[8];
        int4 labn4 = lab4;
        {
            long long rb = (long long)tl * TILE_ROWS + wrow + r_l;
            if (rb >= n_rows) rb = n_rows - 1;
            const float* xr = x + rb * C_DIM + c_l;
#pragma unroll
            for (int i = 0; i < 8; ++i) b[i] = *(const float4*)(xr + i * 4);
            if (epi) {
                long long lb = (long long)tl * TILE_ROWS + wrow + quad * 4;
                if (lb > (long long)n_rows - 4) lb = n_rows - 4;
                labn4 = *(const int4*)(labels + lb);
            }
        }

        // ---- softmax stats (4 lanes per row, depth-2 reduce) ----
        float m = fmax4(a[0]);
#pragma unroll
        for (int i = 1; i < 8; ++i) m = fmaxf(m, fmax4(a[i]));
        float s = 0.f;
#pragma unroll
        for (int i = 0; i < 8; ++i) s += esum4(a[i], m);
#pragma unroll
        for (int mask = 1; mask <= 2; mask <<= 1) {
            float mo = __shfl_xor(m, mask);
            float so = __shfl_xor(s, mask);
            float nm = fmaxf(m, mo);
            s = s * __expf(m - nm) + so * __expf(mo - nm);
            m = nm;
        }
        if ((lane & 3) == 0) lse_lds[wrow + r_l] = m + __logf(s);

        // ---- bf16 convert -> wave-private LDS rows (native packed cvt) ----
        ushort8* dst = (ushort8*)&x_lds[(wrow + r_l) * XSTRIDE + c_l];
#pragma unroll
        for (int i = 0; i < 4; ++i) {
            FragU wv;
            wv.b = cvt8(a[2 * i], a[2 * i + 1]);
            dst[i] = wv.u;
        }
        // same-wave DS ordering: drain writes before fragment reads (no barrier)
        asm volatile("s_waitcnt lgkmcnt(0)" ::: "memory");
        __builtin_amdgcn_sched_barrier(0);

        // ---- MFMA: this wave's 16 rows x all 128 protos ----
        FragU A[4];
#pragma unroll
        for (int kt = 0; kt < 4; ++kt)
            A[kt].u = *(const ushort8*)&x_lds[(wrow + l15) * XSTRIDE + kt * 32 + quad * 8];
        f32x4 acc[8];
        f32x4 zero = {0.f, 0.f, 0.f, 0.f};
#pragma unroll
        for (int nt = 0; nt < 8; ++nt) acc[nt] = zero;
#pragma unroll
        for (int kt = 0; kt < 4; ++kt) {
#pragma unroll
            for (int nt = 0; nt < 8; ++nt) {
                FragU B;
                B.u = *(const ushort8*)&blds[((nt * 4 + kt) * 64 + lane) * 8];
                acc[nt] = __builtin_amdgcn_mfma_f32_16x16x32_bf16(A[kt].b, B.b, acc[nt], 0, 0, 0);
            }
        }

        // ---- in-wave packed argmin over all 128 cols (raw-bit uint min) ----
        // C layout: col = nt*16 + l15, row = quad*4 + rg
        // s' = p2b - acc > 0 always -> IEEE bits uint-ordered; low 7 bits = idx
        unsigned res[4];
#pragma unroll
        for (int rg = 0; rg < 4; ++rg) {
            unsigned u = 0xFFFFFFFFu;
#pragma unroll
            for (int nt = 0; nt < 8; ++nt) {
                unsigned c = (__float_as_uint(p2b[nt] - acc[nt][rg]) & 0xFFFFFF80u)
                           | (unsigned)(nt * 16 + l15);
                u = (c < u) ? c : u;
            }
#pragma unroll
            for (int mask = 1; mask <= 8; mask <<= 1) {
                unsigned uo = __shfl_xor(u, mask);
                u = (uo < u) ? uo : u;
            }
            res[rg] = u;
        }

        // ---- per-wave epilogue (4 lanes, rows quad*4..quad*4+3) ----
        if (epi) {
#pragma unroll
            for (int rg = 0; rg < 4; ++rg) {
                const int row16 = quad * 4 + rg;
                const long long grow = (long long)t * TILE_ROWS + wrow + row16;
                if (grow < n_rows) {
                    int lab;
                    if      (rg == 0) lab = lab4.x;
                    else if (rg == 1) lab = lab4.y;
                    else if (rg == 2) lab = lab4.z;
                    else              lab = lab4.w;
                    const int bj  = (int)(res[rg] & 127u);
                    const int eff = (lab <= kk - 1) ? lab : bj;
                    const float xv = bf2f(x_lds[(wrow + row16) * XSTRIDE + eff]);
                    nll_acc += lse_lds[wrow + row16] - xv;
                }
            }
        }

        // rotate prefetch buffers
#pragma unroll
        for (int i = 0; i < 8; ++i) a[i] = b[i];
        lab4 = labn4;
    }

    // ---- block reduce -> per-block partial (no atomics, no memset) ----
    float v = nll_acc;
#pragma unroll
    for (int mask = 1; mask <= 32; mask <<= 1) v += __shfl_xor(v, mask);
    if (lane == 0) wsum[wave] = v;
    __syncthreads();
    if (tid == 0) partial[blockIdx.x] = wsum[0] + wsum[1] + wsum[2] + wsum[3];
}

extern "C" __global__ void __launch_bounds__(256)
ploss_finalize(const float* __restrict__ partial, float* __restrict__ out,
               float inv_n, int nparts)
{
    __shared__ double sm[4];
    const int tid = threadIdx.x, lane = tid & 63, wave = tid >> 6;
    double v = 0.0;
    for (int i = tid; i < nparts; i += 256) v += (double)partial[i];
#pragma unroll
    for (int mask = 1; mask <= 32; mask <<= 1) v += __shfl_xor(v, mask);
    if (lane == 0) sm[wave] = v;
    __syncthreads();
    if (tid == 0) out[0] = (float)((sm[0] + sm[1] + sm[2] + sm[3]) * (double)inv_n);
}

extern "C" void kernel_launch(void* const* d_in, const int* in_sizes, int n_in,
                              void* d_out, int out_size, void* d_ws, size_t ws_size,
                              hipStream_t stream)
{
    const float* x      = (const float*)d_in[0];
    const int*   labels = (const int*)d_in[1];
    const float* protos = (const float*)d_in[2];
    const int*   kptr   = (const int*)d_in[3];
    const int n_rows  = in_sizes[0] / C_DIM;                 // element counts
    const int n_tiles = (n_rows + TILE_ROWS - 1) / TILE_ROWS; // 400000/64 = 6250

    float* partial = (float*)d_ws;   // overwritten every call; poison-safe

    int grid = GRID_MAX;
    if (grid > n_tiles) grid = n_tiles;
    const int max_parts = (int)(ws_size / sizeof(float));    // workspace guard
    if (grid > max_parts) grid = max_parts;
    if (grid < 1) grid = 1;

    ploss_main<<<grid, NTHREADS, 0, stream>>>(x, labels, protos, kptr, partial,
                                              n_tiles, n_rows);
    ploss_finalize<<<1, 256, 0, stream>>>(partial, (float*)d_out,
                                          1.0f / (float)n_rows, grid);
}

// Round 8
// 292.114 us; speedup vs baseline: 1.3833x; 1.0170x over previous
//
#include <hip/hip_runtime.h>

// PLoss fused kernel, round 10 (= round-9 body, grid 1536 -> 768).
// Round-9 post-mortem: VALU trim = -0.3 us (noise) -> kernel is NOT
// VALU-bound; confirmed latency/schedule-bound. Remaining theory: grid=1536
// at 3 blocks/CU (768 resident) runs TWO sequential block generations; each
// pays the ~3 us prologue (proto staging + norms) and the gen boundary adds a
// drain/refill bubble. Wall model: 2 x (3 + 4x4) ~ 38 us + bubbles ~ 55 us
// observed. grid=768 = exactly one resident generation: prologue once,
// 8 BW-periods of ~4 us -> ~35 us, near the 33 us HBM floor.
// ONLY change: GRID_MAX 1536 -> 768. Kernel body byte-identical to round 9
// (rounds 5-7 proved the allocator punishes any body restructure).
// Verified structure retained:
//  - Wave-private 64-row tiles, ZERO per-tile barriers (wave-private LDS +
//    lgkmcnt fence + sched_barrier - fence REQUIRED, see rule-18 pattern).
//  - Protos staged once as frag-linear bf16 MFMA-B fragments in LDS (32 KB).
//  - Register double-buffer prefetch of next tile's x + labels.
//  - Native packed bf16 cvt; bias-positive raw-bit argmin (p2b = 1024+.5||p||^2,
//    score in (512,2048) -> IEEE bits uint-min-ordered, 7-bit idx in mantissa).
//  - Epilogue: 4 lanes/wave, lse from lse_lds, xv from bf16 x_lds.
//  - partial[blockIdx] overwrite + ws-size guard; finalize sums in double.

#define C_DIM 128
#define TILE_ROWS 64
#define NTHREADS 256
#define XSTRIDE 136           // ushorts per x row: 128 + 8 pad
#define GRID_MAX 768          // = 3 blocks/CU x 256 CU: ONE resident generation
#define NFRAG 32              // 8 n-tiles * 4 k-tiles

typedef __bf16 bf16x8 __attribute__((ext_vector_type(8)));
typedef unsigned short ushort8 __attribute__((ext_vector_type(8)));
typedef float f32x4 __attribute__((ext_vector_type(4)));

union FragU { ushort8 u; bf16x8 b; };

__device__ __forceinline__ float bf2f(unsigned short h) {
    return __uint_as_float(((unsigned int)h) << 16);
}
__device__ __forceinline__ float fmax4(float4 v) {
    return fmaxf(fmaxf(v.x, v.y), fmaxf(v.z, v.w));
}
__device__ __forceinline__ float esum4(float4 v, float m) {
    return __expf(v.x - m) + __expf(v.y - m) + __expf(v.z - m) + __expf(v.w - m);
}
__device__ __forceinline__ float dot4(float4 v) {
    return v.x*v.x + v.y*v.y + v.z*v.z + v.w*v.w;
}
__device__ __forceinline__ bf16x8 cvt8(float4 lo, float4 hi) {   // RTNE, packed
    bf16x8 r;
    r[0]=(__bf16)lo.x; r[1]=(__bf16)lo.y; r[2]=(__bf16)lo.z; r[3]=(__bf16)lo.w;
    r[4]=(__bf16)hi.x; r[5]=(__bf16)hi.y; r[6]=(__bf16)hi.z; r[7]=(__bf16)hi.w;
    return r;
}

extern "C" __global__ void __launch_bounds__(NTHREADS, 3)
ploss_main(const float* __restrict__ x, const int* __restrict__ labels,
           const float* __restrict__ protos, const int* __restrict__ kptr,
           float* __restrict__ partial, int n_tiles, int n_rows)
{
    // 32768 + 17408 + 256 + 512 + 16 = 50.9 KB -> 3 blocks/CU
    __shared__ __attribute__((aligned(16))) unsigned short blds[NFRAG * 64 * 8];
    __shared__ __attribute__((aligned(16))) unsigned short x_lds[TILE_ROWS * XSTRIDE];
    __shared__ float lse_lds[TILE_ROWS];
    __shared__ float norm_lds[C_DIM];
    __shared__ float wsum[4];

    const int tid  = threadIdx.x;
    const int lane = tid & 63;
    const int wave = tid >> 6;
    const int l15  = lane & 15;
    const int quad = lane >> 4;
    const int r_l  = lane >> 2;         // row 0..15 within wave's 16 (load/softmax)
    const int c_l  = (lane & 3) * 32;   // 32-col chunk within row
    const int wrow = wave * 16;
    const bool epi = (l15 == 0);
    const int kk   = kptr[0];

    // ---- prologue: proto squared norms (2 threads per proto) ----
    {
        const int j = tid >> 1;
        const float* pr = protos + j * C_DIM + (tid & 1) * 64;
        float s = 0.f;
#pragma unroll
        for (int c = 0; c < 64; c += 4) {
            float4 v = *(const float4*)(pr + c);
            s += dot4(v);
        }
        s += __shfl_xor(s, 1);
        if ((tid & 1) == 0) norm_lds[j] = s;
    }
    // ---- prologue: protos -> frag-linear bf16 MFMA-B fragments in LDS ----
    // frag id = nt*4+kt; lane l holds col nt*16+(l&15), k = kt*32+(l>>4)*8..+8
#pragma unroll
    for (int f = 0; f < 8; ++f) {
        const int g = f * NTHREADS + tid;       // 0..2047 = frag*64 + lane
        const int l = g & 63;
        const int frag = g >> 6;
        const int nt = frag >> 2, kt = frag & 3;
        const float* pp = protos + (nt * 16 + (l & 15)) * C_DIM + kt * 32 + (l >> 4) * 8;
        float4 v0 = *(const float4*)(pp);
        float4 v1 = *(const float4*)(pp + 4);
        FragU fr;
        fr.b = cvt8(v0, v1);
        *(ushort8*)&blds[g * 8] = fr.u;
    }
    __syncthreads();   // blds + norm_lds ready; no further barriers until reduce

    // biased half-norms: s' = p2b - x.p  in (512, 2048) -> positive, fixed exp
    float p2b[8];
#pragma unroll
    for (int nt = 0; nt < 8; ++nt) p2b[nt] = 1024.0f + 0.5f * norm_lds[nt * 16 + l15];

    float nll_acc = 0.f;

    // ---- prologue: load first tile into registers ----
    int t = blockIdx.x;
    float4 a[8];
    int4 lab4 = {0, 0, 0, 0};
    {
        long long rb = (long long)t * TILE_ROWS + wrow + r_l;
        if (rb >= n_rows) rb = n_rows - 1;
        const float* xr = x + rb * C_DIM + c_l;
#pragma unroll
        for (int i = 0; i < 8; ++i) a[i] = *(const float4*)(xr + i * 4);
        if (epi) {
            long long lb = (long long)t * TILE_ROWS + wrow + quad * 4;
            if (lb > (long long)n_rows - 4) lb = n_rows - 4;
            lab4 = *(const int4*)(labels + lb);
        }
    }

    for (; t < n_tiles; t += gridDim.x) {
        // ---- prefetch next tile (x + labels) into shadow registers ----
        const int tn = t + gridDim.x;
        const int tl = (tn < n_tiles) ? tn : t;    // clamp: tail load discarded
        float4 b[8];
        int4 labn4 = lab4;
        {
            long long rb = (long long)tl * TILE_ROWS + wrow + r_l;
            if (rb >= n_rows) rb = n_rows - 1;
            const float* xr = x + rb * C_DIM + c_l;
#pragma unroll
            for (int i = 0; i < 8; ++i) b[i] = *(const float4*)(xr + i * 4);
            if (epi) {
                long long lb = (long long)tl * TILE_ROWS + wrow + quad * 4;
                if (lb > (long long)n_rows - 4) lb = n_rows - 4;
                labn4 = *(const int4*)(labels + lb);
            }
        }

        // ---- softmax stats (4 lanes per row, depth-2 reduce) ----
        float m = fmax4(a[0]);
#pragma unroll
        for (int i = 1; i < 8; ++i) m = fmaxf(m, fmax4(a[i]));
        float s = 0.f;
#pragma unroll
        for (int i = 0; i < 8; ++i) s += esum4(a[i], m);
#pragma unroll
        for (int mask = 1; mask <= 2; mask <<= 1) {
            float mo = __shfl_xor(m, mask);
            float so = __shfl_xor(s, mask);
            float nm = fmaxf(m, mo);
            s = s * __expf(m - nm) + so * __expf(mo - nm);
            m = nm;
        }
        if ((lane & 3) == 0) lse_lds[wrow + r_l] = m + __logf(s);

        // ---- bf16 convert -> wave-private LDS rows (native packed cvt) ----
        ushort8* dst = (ushort8*)&x_lds[(wrow + r_l) * XSTRIDE + c_l];
#pragma unroll
        for (int i = 0; i < 4; ++i) {
            FragU wv;
            wv.b = cvt8(a[2 * i], a[2 * i + 1]);
            dst[i] = wv.u;
        }
        // same-wave DS ordering: drain writes before fragment reads (no barrier)
        asm volatile("s_waitcnt lgkmcnt(0)" ::: "memory");
        __builtin_amdgcn_sched_barrier(0);

        // ---- MFMA: this wave's 16 rows x all 128 protos ----
        FragU A[4];
#pragma unroll
        for (int kt = 0; kt < 4; ++kt)
            A[kt].u = *(const ushort8*)&x_lds[(wrow + l15) * XSTRIDE + kt * 32 + quad * 8];
        f32x4 acc[8];
        f32x4 zero = {0.f, 0.f, 0.f, 0.f};
#pragma unroll
        for (int nt = 0; nt < 8; ++nt) acc[nt] = zero;
#pragma unroll
        for (int kt = 0; kt < 4; ++kt) {
#pragma unroll
            for (int nt = 0; nt < 8; ++nt) {
                FragU B;
                B.u = *(const ushort8*)&blds[((nt * 4 + kt) * 64 + lane) * 8];
                acc[nt] = __builtin_amdgcn_mfma_f32_16x16x32_bf16(A[kt].b, B.b, acc[nt], 0, 0, 0);
            }
        }

        // ---- in-wave packed argmin over all 128 cols (raw-bit uint min) ----
        // C layout: col = nt*16 + l15, row = quad*4 + rg
        // s' = p2b - acc > 0 always -> IEEE bits uint-ordered; low 7 bits = idx
        unsigned res[4];
#pragma unroll
        for (int rg = 0; rg < 4; ++rg) {
            unsigned u = 0xFFFFFFFFu;
#pragma unroll
            for (int nt = 0; nt < 8; ++nt) {
                unsigned c = (__float_as_uint(p2b[nt] - acc[nt][rg]) & 0xFFFFFF80u)
                           | (unsigned)(nt * 16 + l15);
                u = (c < u) ? c : u;
            }
#pragma unroll
            for (int mask = 1; mask <= 8; mask <<= 1) {
                unsigned uo = __shfl_xor(u, mask);
                u = (uo < u) ? uo : u;
            }
            res[rg] = u;
        }

        // ---- per-wave epilogue (4 lanes, rows quad*4..quad*4+3) ----
        if (epi) {
#pragma unroll
            for (int rg = 0; rg < 4; ++rg) {
                const int row16 = quad * 4 + rg;
                const long long grow = (long long)t * TILE_ROWS + wrow + row16;
                if (grow < n_rows) {
                    int lab;
                    if      (rg == 0) lab = lab4.x;
                    else if (rg == 1) lab = lab4.y;
                    else if (rg == 2) lab = lab4.z;
                    else              lab = lab4.w;
                    const int bj  = (int)(res[rg] & 127u);
                    const int eff = (lab <= kk - 1) ? lab : bj;
                    const float xv = bf2f(x_lds[(wrow + row16) * XSTRIDE + eff]);
                    nll_acc += lse_lds[wrow + row16] - xv;
                }
            }
        }

        // rotate prefetch buffers
#pragma unroll
        for (int i = 0; i < 8; ++i) a[i] = b[i];
        lab4 = labn4;
    }

    // ---- block reduce -> per-block partial (no atomics, no memset) ----
    float v = nll_acc;
#pragma unroll
    for (int mask = 1; mask <= 32; mask <<= 1) v += __shfl_xor(v, mask);
    if (lane == 0) wsum[wave] = v;
    __syncthreads();
    if (tid == 0) partial[blockIdx.x] = wsum[0] + wsum[1] + wsum[2] + wsum[3];
}

extern "C" __global__ void __launch_bounds__(256)
ploss_finalize(const float* __restrict__ partial, float* __restrict__ out,
               float inv_n, int nparts)
{
    __shared__ double sm[4];
    const int tid = threadIdx.x, lane = tid & 63, wave = tid >> 6;
    double v = 0.0;
    for (int i = tid; i < nparts; i += 256) v += (double)partial[i];
#pragma unroll
    for (int mask = 1; mask <= 32; mask <<= 1) v += __shfl_xor(v, mask);
    if (lane == 0) sm[wave] = v;
    __syncthreads();
    if (tid == 0) out[0] = (float)((sm[0] + sm[1] + sm[2] + sm[3]) * (double)inv_n);
}

extern "C" void kernel_launch(void* const* d_in, const int* in_sizes, int n_in,
                              void* d_out, int out_size, void* d_ws, size_t ws_size,
                              hipStream_t stream)
{
    const float* x      = (const float*)d_in[0];
    const int*   labels = (const int*)d_in[1];
    const float* protos = (const float*)d_in[2];
    const int*   kptr   = (const int*)d_in[3];
    const int n_rows  = in_sizes[0] / C_DIM;                 // element counts
    const int n_tiles = (n_rows + TILE_ROWS - 1) / TILE_ROWS; // 400000/64 = 6250

    float* partial = (float*)d_ws;   // overwritten every call; poison-safe

    int grid = GRID_MAX;
    if (grid > n_tiles) grid = n_tiles;
    const int max_parts = (int)(ws_size / sizeof(float));    // workspace guard
    if (grid > max_parts) grid = max_parts;
    if (grid < 1) grid = 1;

    ploss_main<<<grid, NTHREADS, 0, stream>>>(x, labels, protos, kptr, partial,
                                              n_tiles, n_rows);
    ploss_finalize<<<1, 256, 0, stream>>>(partial, (float*)d_out,
                                          1.0f / (float)n_rows, grid);
}